// Round 1
// baseline (1897.870 us; speedup 1.0000x reference)
//
#include <hip/hip_runtime.h>

// ODE-RNN encoder: B=2048, T=64, HID=16, adaptive Tsit5 (fixed 16 scan iters) + GRU.
// Layout: 16 lanes per sample (lane j holds element j of the hidden state),
// 4 samples per wave, 512 blocks x 64 threads.
// Matvec via ds_swizzle 16-lane broadcasts against per-lane weight rows in VGPRs.

#define T_STEPS 64
#define NB 2048
#define N_ODE_STEPS 16

// broadcast lane I (0..15) of the 16-lane group: BitMode and=0x10 (keep group bit), or=I
#define BC(v, I) __int_as_float(__builtin_amdgcn_ds_swizzle(__float_as_int(v), (((I) << 5) | 0x10)))
// xor-butterfly within 16-lane group (masks 1,2,4,8): and=0x1f, xor=M
#define SWX(v, M) __int_as_float(__builtin_amdgcn_ds_swizzle(__float_as_int(v), (((M) << 10) | 0x1f)))

__device__ __forceinline__ float rsum16(float v) {
  v += SWX(v, 1);
  v += SWX(v, 2);
  v += SWX(v, 4);
  v += SWX(v, 8);
  return v;  // all 16 lanes hold the group sum
}

__device__ __forceinline__ float dot16(const float (&w)[16], float y) {
  // 4 independent accumulator chains for ILP
  float a0 = w[0] * BC(y, 0);
  float a1 = w[1] * BC(y, 1);
  float a2 = w[2] * BC(y, 2);
  float a3 = w[3] * BC(y, 3);
  a0 = fmaf(w[4], BC(y, 4), a0);
  a1 = fmaf(w[5], BC(y, 5), a1);
  a2 = fmaf(w[6], BC(y, 6), a2);
  a3 = fmaf(w[7], BC(y, 7), a3);
  a0 = fmaf(w[8], BC(y, 8), a0);
  a1 = fmaf(w[9], BC(y, 9), a1);
  a2 = fmaf(w[10], BC(y, 10), a2);
  a3 = fmaf(w[11], BC(y, 11), a3);
  a0 = fmaf(w[12], BC(y, 12), a0);
  a1 = fmaf(w[13], BC(y, 13), a1);
  a2 = fmaf(w[14], BC(y, 14), a2);
  a3 = fmaf(w[15], BC(y, 15), a3);
  return (a0 + a1) + (a2 + a3);
}

__device__ __forceinline__ float fast_tanh(float x) {
  // tanh(x) = 1 - 2/(exp(2x)+1)  (exact identity; __expf + v_rcp ~1e-7 abs err)
  float e = __expf(2.0f * x);
  return fmaf(-2.0f, __builtin_amdgcn_rcpf(e + 1.0f), 1.0f);
}

__device__ __forceinline__ float sigmoid_(float x) {
  return 1.0f / (1.0f + __expf(-x));
}

__device__ __forceinline__ float mlp_f(float y,
    const float (&w1r)[16], float b1v,
    const float (&w2r)[16], float b2v,
    const float (&w3r)[16], float b3v) {
  float h1 = fast_tanh(dot16(w1r, y) + b1v);
  float h2 = fast_tanh(dot16(w2r, h1) + b2v);
  return dot16(w3r, h2) + b3v;
}

__global__ __launch_bounds__(64, 1) void odern_kernel(
    const float* __restrict__ x_seq,
    const float* __restrict__ w1, const float* __restrict__ b1,
    const float* __restrict__ w2, const float* __restrict__ b2,
    const float* __restrict__ w3, const float* __restrict__ b3,
    const float* __restrict__ gru_wih, const float* __restrict__ gru_whh,
    const float* __restrict__ gru_b, const float* __restrict__ gru_bn,
    const float* __restrict__ pred_w, const float* __restrict__ pred_b,
    float* __restrict__ out) {
  const int tid = threadIdx.x;
  const int j = tid & 15;        // hidden index owned by this lane
  const int g = tid >> 4;        // sample-in-wave 0..3
  const int b = blockIdx.x * 4 + g;

  // per-lane weight rows (kept in VGPRs; all indexing is compile-time constant)
  float w1r[16], w2r[16], w3r[16], whr[16], wzr[16], wnr[16];
#pragma unroll
  for (int i = 0; i < 16; ++i) {
    w1r[i] = w1[j * 16 + i];
    w2r[i] = w2[j * 16 + i];
    w3r[i] = w3[j * 16 + i];
    whr[i] = gru_whh[j * 16 + i];
    wzr[i] = gru_whh[(16 + j) * 16 + i];
    wnr[i] = gru_whh[(32 + j) * 16 + i];
  }
  const float b1v = b1[j], b2v = b2[j], b3v = b3[j];
  const float wih_r0 = gru_wih[j * 2],        wih_r1 = gru_wih[j * 2 + 1];
  const float wih_z0 = gru_wih[(16 + j) * 2], wih_z1 = gru_wih[(16 + j) * 2 + 1];
  const float wih_n0 = gru_wih[(32 + j) * 2], wih_n1 = gru_wih[(32 + j) * 2 + 1];
  const float gb_r = gru_b[j], gb_z = gru_b[16 + j], gb_n = gru_b[32 + j];
  const float bnv = gru_bn[j];
  const float pwv = pred_w[j], pbv = pred_b[0];

  const float* xp = x_seq + (size_t)b * (T_STEPS * 2);

  float h = 0.0f;
#pragma unroll 1
  for (int t = 0; t < T_STEPS; ++t) {
    const float x0 = xp[2 * t];       // hoistable loads, latency hidden over ODE solve
    const float x1 = xp[2 * t + 1];

    // ---- adaptive Tsit5 from t=0 to t=1, fixed 16 iterations ----
    float y = h;
    float tt = 0.0f, dt = 1.0f;
    float k1 = mlp_f(y, w1r, b1v, w2r, b2v, w3r, b3v);
#pragma unroll 1
    for (int s = 0; s < N_ODE_STEPS; ++s) {
      const float dt_c = fminf(dt, 1.0f - tt);
      const float d = dt_c;

      float s2 = 0.161f * k1;
      float k2 = mlp_f(fmaf(d, s2, y), w1r, b1v, w2r, b2v, w3r, b3v);

      float s3 = fmaf(0.335480655492357f, k2, -0.008480655492356989f * k1);
      float k3 = mlp_f(fmaf(d, s3, y), w1r, b1v, w2r, b2v, w3r, b3v);

      float s4 = fmaf(4.3622954328695815f, k3,
                 fmaf(-6.359448489975075f, k2, 2.8971530571054935f * k1));
      float k4 = mlp_f(fmaf(d, s4, y), w1r, b1v, w2r, b2v, w3r, b3v);

      float s5 = fmaf(-0.09249506636175525f, k4,
                 fmaf(7.4955393428898365f, k3,
                 fmaf(-11.748883564062828f, k2, 5.325864828439257f * k1)));
      float k5 = mlp_f(fmaf(d, s5, y), w1r, b1v, w2r, b2v, w3r, b3v);

      float s6 = fmaf(-0.028269050394068383f, k5,
                 fmaf(-0.071584973281401f, k4,
                 fmaf(8.159367898576159f, k3,
                 fmaf(-12.92096931784711f, k2, 5.86145544294642f * k1))));
      float k6 = mlp_f(fmaf(d, s6, y), w1r, b1v, w2r, b2v, w3r, b3v);

      float sy = fmaf(2.324710524099774f, k6,
                 fmaf(-3.290069515436081f, k5,
                 fmaf(1.379008574103742f, k4,
                 fmaf(0.4798896504144996f, k3,
                 fmaf(0.01f, k2, 0.09646076681806523f * k1)))));
      float y_new = fmaf(d, sy, y);

      float k7 = mlp_f(y_new, w1r, b1v, w2r, b2v, w3r, b3v);

      float se = fmaf(0.015151515151515152f, k7,
                 fmaf(-0.45808210592918697f, k6,
                 fmaf(0.5823571654525552f, k5,
                 fmaf(-0.1447110071732629f, k4,
                 fmaf(0.007880878010261995f, k3,
                 fmaf(-0.0008164344596567469f, k2, -0.001780011052225777f * k1))))));
      float err = d * se;

      float scale = fmaf(0.01f, fmaxf(fabsf(y), fabsf(y_new)), 0.0001f);
      float r = err / scale;
      float m = rsum16(r * r) * 0.0625f;   // mean over the 16 hidden dims
      float err2 = fmaxf(m, 1e-16f);

      const bool acc = err2 <= 1.0f;
      y = acc ? y_new : y;
      tt = acc ? tt + dt_c : tt;
      k1 = acc ? k7 : k1;   // FSAL: f(y_new) == k7 bitwise (deterministic), else keep k1

      float fac = 0.9f * __expf(-0.1f * __logf(err2));
      fac = fminf(fmaxf(fac, 0.2f), 10.0f);
      dt = dt_c * fac;
    }

    // ---- GRU update: h = n + z*(h_ev - n), h_ev = y ----
    float hr = dot16(whr, y);
    float hz = dot16(wzr, y);
    float hn = dot16(wnr, y);
    float ir = fmaf(wih_r1, x1, fmaf(wih_r0, x0, gb_r));
    float iz = fmaf(wih_z1, x1, fmaf(wih_z0, x0, gb_z));
    float in_ = fmaf(wih_n1, x1, fmaf(wih_n0, x0, gb_n));
    float rg = sigmoid_(ir + hr);
    float zg = sigmoid_(iz + hz);
    float ng = fast_tanh(fmaf(rg, hn + bnv, in_));
    h = fmaf(zg, y - ng, ng);
  }

  // ---- final projection: out[b] = h . pred_w + pred_b ----
  float ps = rsum16(h * pwv);
  if (j == 0) out[b] = ps + pbv;
}

extern "C" void kernel_launch(void* const* d_in, const int* in_sizes, int n_in,
                              void* d_out, int out_size, void* d_ws, size_t ws_size,
                              hipStream_t stream) {
  (void)in_sizes; (void)n_in; (void)out_size; (void)d_ws; (void)ws_size;
  odern_kernel<<<dim3(NB / 4), dim3(64), 0, stream>>>(
      (const float*)d_in[0],
      (const float*)d_in[1], (const float*)d_in[2],
      (const float*)d_in[3], (const float*)d_in[4],
      (const float*)d_in[5], (const float*)d_in[6],
      (const float*)d_in[7], (const float*)d_in[8],
      (const float*)d_in[9], (const float*)d_in[10],
      (const float*)d_in[11], (const float*)d_in[12],
      (float*)d_out);
}

// Round 4
// 1447.781 us; speedup vs baseline: 1.3109x; 1.3109x over previous
//
#include <hip/hip_runtime.h>

// ODE-RNN encoder: B=2048, T=64, HID=16, adaptive Tsit5 (fixed 16 iters) + GRU.
// Layout: 16 lanes per sample (lane j owns h[j]), 4 samples/wave, 512 blocks x 64.
// Round 4: matvec via DPP row_ror rotate+FMA against pre-permuted weight rows
// (pure VALU, zero DS-pipe traffic). Builtins: exp2f + logf (logf IS log2 on amdgcn).

#define T_STEPS 64
#define NB 2048
#define N_ODE_STEPS 16

// row_ror:r  => dst lane n gets src lane (n - r) & 15 (within 16-lane row)
#define ROR(x, r) __int_as_float(__builtin_amdgcn_update_dpp( \
    0, __float_as_int(x), 0x120 + (r), 0xF, 0xF, true))

__device__ __forceinline__ float rsum16(float v) {
  v += ROR(v, 8);
  v += ROR(v, 4);
  v += ROR(v, 2);
  v += ROR(v, 1);
  return v;  // all 16 lanes hold the row sum
}

// w[r] must hold W[j][(j - r) & 15] for this lane's row j.
__device__ __forceinline__ float dot16(const float (&w)[16], float y) {
  float a0 = w[0] * y;               // r = 0: identity
  float a1 = w[1] * ROR(y, 1);
  float a2 = w[2] * ROR(y, 2);
  float a3 = w[3] * ROR(y, 3);
  a0 = fmaf(w[4],  ROR(y, 4),  a0);
  a1 = fmaf(w[5],  ROR(y, 5),  a1);
  a2 = fmaf(w[6],  ROR(y, 6),  a2);
  a3 = fmaf(w[7],  ROR(y, 7),  a3);
  a0 = fmaf(w[8],  ROR(y, 8),  a0);
  a1 = fmaf(w[9],  ROR(y, 9),  a1);
  a2 = fmaf(w[10], ROR(y, 10), a2);
  a3 = fmaf(w[11], ROR(y, 11), a3);
  a0 = fmaf(w[12], ROR(y, 12), a0);
  a1 = fmaf(w[13], ROR(y, 13), a1);
  a2 = fmaf(w[14], ROR(y, 14), a2);
  a3 = fmaf(w[15], ROR(y, 15), a3);
  return (a0 + a1) + (a2 + a3);
}

__device__ __forceinline__ float fast_tanh(float x) {
  // tanh(x) = 1 - 2/(exp(2x)+1); exp via v_exp_f32 (computes 2^x)
  float e = __builtin_amdgcn_exp2f(x * 2.885390081777927f);  // 2*log2(e)
  return fmaf(-2.0f, __builtin_amdgcn_rcpf(e + 1.0f), 1.0f);
}

__device__ __forceinline__ float sigmoid_(float x) {
  float e = __builtin_amdgcn_exp2f(x * -1.4426950408889634f);
  return __builtin_amdgcn_rcpf(1.0f + e);
}

__device__ __forceinline__ float mlp_f(float y,
    const float (&w1r)[16], float b1v,
    const float (&w2r)[16], float b2v,
    const float (&w3r)[16], float b3v) {
  float h1 = fast_tanh(dot16(w1r, y) + b1v);
  float h2 = fast_tanh(dot16(w2r, h1) + b2v);
  return dot16(w3r, h2) + b3v;
}

__global__ __launch_bounds__(64, 1) void odern_kernel(
    const float* __restrict__ x_seq,
    const float* __restrict__ w1, const float* __restrict__ b1,
    const float* __restrict__ w2, const float* __restrict__ b2,
    const float* __restrict__ w3, const float* __restrict__ b3,
    const float* __restrict__ gru_wih, const float* __restrict__ gru_whh,
    const float* __restrict__ gru_b, const float* __restrict__ gru_bn,
    const float* __restrict__ pred_w, const float* __restrict__ pred_b,
    float* __restrict__ out) {
  const int tid = threadIdx.x;
  const int j = tid & 15;        // hidden index owned by this lane
  const int g = tid >> 4;        // sample-in-wave 0..3
  const int b = blockIdx.x * 4 + g;

  // per-lane weight rows, pre-permuted for the ROR schedule:
  // w[r] = W[j][(j - r) & 15]
  float w1r[16], w2r[16], w3r[16], whr[16], wzr[16], wnr[16];
#pragma unroll
  for (int r = 0; r < 16; ++r) {
    const int i = (j - r) & 15;
    w1r[r] = w1[j * 16 + i];
    w2r[r] = w2[j * 16 + i];
    w3r[r] = w3[j * 16 + i];
    whr[r] = gru_whh[j * 16 + i];
    wzr[r] = gru_whh[(16 + j) * 16 + i];
    wnr[r] = gru_whh[(32 + j) * 16 + i];
  }
  const float b1v = b1[j], b2v = b2[j], b3v = b3[j];
  const float wih_r0 = gru_wih[j * 2],        wih_r1 = gru_wih[j * 2 + 1];
  const float wih_z0 = gru_wih[(16 + j) * 2], wih_z1 = gru_wih[(16 + j) * 2 + 1];
  const float wih_n0 = gru_wih[(32 + j) * 2], wih_n1 = gru_wih[(32 + j) * 2 + 1];
  const float gb_r = gru_b[j], gb_z = gru_b[16 + j], gb_n = gru_b[32 + j];
  const float bnv = gru_bn[j];
  const float pwv = pred_w[j], pbv = pred_b[0];

  const float* xp = x_seq + (size_t)b * (T_STEPS * 2);

  float h = 0.0f;
#pragma unroll 1
  for (int t = 0; t < T_STEPS; ++t) {
    const float x0 = xp[2 * t];
    const float x1 = xp[2 * t + 1];

    // ---- adaptive Tsit5 from t=0 to t=1, fixed 16 iterations ----
    float y = h;
    float tt = 0.0f, dt = 1.0f;
    float k1 = mlp_f(y, w1r, b1v, w2r, b2v, w3r, b3v);
#pragma unroll 1
    for (int s = 0; s < N_ODE_STEPS; ++s) {
      const float dt_c = fminf(dt, 1.0f - tt);
      const float d = dt_c;

      float s2 = 0.161f * k1;
      float k2 = mlp_f(fmaf(d, s2, y), w1r, b1v, w2r, b2v, w3r, b3v);

      float s3 = fmaf(0.335480655492357f, k2, -0.008480655492356989f * k1);
      float k3 = mlp_f(fmaf(d, s3, y), w1r, b1v, w2r, b2v, w3r, b3v);

      float s4 = fmaf(4.3622954328695815f, k3,
                 fmaf(-6.359448489975075f, k2, 2.8971530571054935f * k1));
      float k4 = mlp_f(fmaf(d, s4, y), w1r, b1v, w2r, b2v, w3r, b3v);

      float s5 = fmaf(-0.09249506636175525f, k4,
                 fmaf(7.4955393428898365f, k3,
                 fmaf(-11.748883564062828f, k2, 5.325864828439257f * k1)));
      float k5 = mlp_f(fmaf(d, s5, y), w1r, b1v, w2r, b2v, w3r, b3v);

      float s6 = fmaf(-0.028269050394068383f, k5,
                 fmaf(-0.071584973281401f, k4,
                 fmaf(8.159367898576159f, k3,
                 fmaf(-12.92096931784711f, k2, 5.86145544294642f * k1))));
      float k6 = mlp_f(fmaf(d, s6, y), w1r, b1v, w2r, b2v, w3r, b3v);

      float sy = fmaf(2.324710524099774f, k6,
                 fmaf(-3.290069515436081f, k5,
                 fmaf(1.379008574103742f, k4,
                 fmaf(0.4798896504144996f, k3,
                 fmaf(0.01f, k2, 0.09646076681806523f * k1)))));
      float y_new = fmaf(d, sy, y);

      float k7 = mlp_f(y_new, w1r, b1v, w2r, b2v, w3r, b3v);

      float se = fmaf(0.015151515151515152f, k7,
                 fmaf(-0.45808210592918697f, k6,
                 fmaf(0.5823571654525552f, k5,
                 fmaf(-0.1447110071732629f, k4,
                 fmaf(0.007880878010261995f, k3,
                 fmaf(-0.0008164344596567469f, k2, -0.001780011052225777f * k1))))));
      float err = d * se;

      float scale = fmaf(0.01f, fmaxf(fabsf(y), fabsf(y_new)), 0.0001f);
      float r = err * __builtin_amdgcn_rcpf(scale);
      float m = rsum16(r * r) * 0.0625f;   // mean over the 16 hidden dims
      float err2 = fmaxf(m, 1e-16f);

      const bool acc = err2 <= 1.0f;
      y = acc ? y_new : y;
      tt = acc ? tt + dt_c : tt;
      k1 = acc ? k7 : k1;   // FSAL: f(y_new) == k7 bitwise, else keep k1

      // err2^(-0.1) = exp2(-0.1 * log2(err2)); amdgcn logf IS v_log_f32 = log2
      float fac = 0.9f * __builtin_amdgcn_exp2f(-0.1f * __builtin_amdgcn_logf(err2));
      fac = fminf(fmaxf(fac, 0.2f), 10.0f);
      dt = dt_c * fac;
    }

    // ---- GRU update: h = n + z*(h_ev - n), h_ev = y ----
    float hr = dot16(whr, y);
    float hz = dot16(wzr, y);
    float hn = dot16(wnr, y);
    float ir = fmaf(wih_r1, x1, fmaf(wih_r0, x0, gb_r));
    float iz = fmaf(wih_z1, x1, fmaf(wih_z0, x0, gb_z));
    float in_ = fmaf(wih_n1, x1, fmaf(wih_n0, x0, gb_n));
    float rg = sigmoid_(ir + hr);
    float zg = sigmoid_(iz + hz);
    float ng = fast_tanh(fmaf(rg, hn + bnv, in_));
    h = fmaf(zg, y - ng, ng);
  }

  // ---- final projection: out[b] = h . pred_w + pred_b ----
  float ps = rsum16(h * pwv);
  if (j == 0) out[b] = ps + pbv;
}

extern "C" void kernel_launch(void* const* d_in, const int* in_sizes, int n_in,
                              void* d_out, int out_size, void* d_ws, size_t ws_size,
                              hipStream_t stream) {
  (void)in_sizes; (void)n_in; (void)out_size; (void)d_ws; (void)ws_size;
  odern_kernel<<<dim3(NB / 4), dim3(64), 0, stream>>>(
      (const float*)d_in[0],
      (const float*)d_in[1], (const float*)d_in[2],
      (const float*)d_in[3], (const float*)d_in[4],
      (const float*)d_in[5], (const float*)d_in[6],
      (const float*)d_in[7], (const float*)d_in[8],
      (const float*)d_in[9], (const float*)d_in[10],
      (const float*)d_in[11], (const float*)d_in[12],
      (float*)d_out);
}

// Round 5
// 192.686 us; speedup vs baseline: 9.8495x; 7.5137x over previous
//
#include <hip/hip_runtime.h>

// ODE-RNN encoder: B=2048, T=64, HID=16, adaptive Tsit5 + GRU.
// Layout: 16 lanes per sample (lane j owns h[j]), 4 samples/wave, 512 blocks x 64.
// Round 5: early-exit the ODE loop when all samples in the wave have t >= 1.
// Exact: once t==1.0 (and t reaches exactly 1.0 in fp), remaining reference
// iterations are bitwise no-ops (d=0 -> y_new=y, err=0, t+=0).

#define T_STEPS 64
#define NB 2048
#define N_ODE_STEPS 16

// row_ror:r  => dst lane n gets src lane (n - r) & 15 (within 16-lane row)
#define ROR(x, r) __int_as_float(__builtin_amdgcn_update_dpp( \
    0, __float_as_int(x), 0x120 + (r), 0xF, 0xF, true))

__device__ __forceinline__ float rsum16(float v) {
  v += ROR(v, 8);
  v += ROR(v, 4);
  v += ROR(v, 2);
  v += ROR(v, 1);
  return v;  // all 16 lanes hold the row sum
}

// w[r] must hold W[j][(j - r) & 15] for this lane's row j.
__device__ __forceinline__ float dot16(const float (&w)[16], float y) {
  float a0 = w[0] * y;               // r = 0: identity
  float a1 = w[1] * ROR(y, 1);
  float a2 = w[2] * ROR(y, 2);
  float a3 = w[3] * ROR(y, 3);
  a0 = fmaf(w[4],  ROR(y, 4),  a0);
  a1 = fmaf(w[5],  ROR(y, 5),  a1);
  a2 = fmaf(w[6],  ROR(y, 6),  a2);
  a3 = fmaf(w[7],  ROR(y, 7),  a3);
  a0 = fmaf(w[8],  ROR(y, 8),  a0);
  a1 = fmaf(w[9],  ROR(y, 9),  a1);
  a2 = fmaf(w[10], ROR(y, 10), a2);
  a3 = fmaf(w[11], ROR(y, 11), a3);
  a0 = fmaf(w[12], ROR(y, 12), a0);
  a1 = fmaf(w[13], ROR(y, 13), a1);
  a2 = fmaf(w[14], ROR(y, 14), a2);
  a3 = fmaf(w[15], ROR(y, 15), a3);
  return (a0 + a1) + (a2 + a3);
}

__device__ __forceinline__ float fast_tanh(float x) {
  // tanh(x) = 1 - 2/(exp(2x)+1); exp via v_exp_f32 (computes 2^x)
  float e = __builtin_amdgcn_exp2f(x * 2.885390081777927f);  // 2*log2(e)
  return fmaf(-2.0f, __builtin_amdgcn_rcpf(e + 1.0f), 1.0f);
}

__device__ __forceinline__ float sigmoid_(float x) {
  float e = __builtin_amdgcn_exp2f(x * -1.4426950408889634f);
  return __builtin_amdgcn_rcpf(1.0f + e);
}

__device__ __forceinline__ float mlp_f(float y,
    const float (&w1r)[16], float b1v,
    const float (&w2r)[16], float b2v,
    const float (&w3r)[16], float b3v) {
  float h1 = fast_tanh(dot16(w1r, y) + b1v);
  float h2 = fast_tanh(dot16(w2r, h1) + b2v);
  return dot16(w3r, h2) + b3v;
}

__global__ __launch_bounds__(64, 1) void odern_kernel(
    const float* __restrict__ x_seq,
    const float* __restrict__ w1, const float* __restrict__ b1,
    const float* __restrict__ w2, const float* __restrict__ b2,
    const float* __restrict__ w3, const float* __restrict__ b3,
    const float* __restrict__ gru_wih, const float* __restrict__ gru_whh,
    const float* __restrict__ gru_b, const float* __restrict__ gru_bn,
    const float* __restrict__ pred_w, const float* __restrict__ pred_b,
    float* __restrict__ out) {
  const int tid = threadIdx.x;
  const int j = tid & 15;        // hidden index owned by this lane
  const int g = tid >> 4;        // sample-in-wave 0..3
  const int b = blockIdx.x * 4 + g;

  // per-lane weight rows, pre-permuted for the ROR schedule:
  // w[r] = W[j][(j - r) & 15]
  float w1r[16], w2r[16], w3r[16], whr[16], wzr[16], wnr[16];
#pragma unroll
  for (int r = 0; r < 16; ++r) {
    const int i = (j - r) & 15;
    w1r[r] = w1[j * 16 + i];
    w2r[r] = w2[j * 16 + i];
    w3r[r] = w3[j * 16 + i];
    whr[r] = gru_whh[j * 16 + i];
    wzr[r] = gru_whh[(16 + j) * 16 + i];
    wnr[r] = gru_whh[(32 + j) * 16 + i];
  }
  const float b1v = b1[j], b2v = b2[j], b3v = b3[j];
  const float wih_r0 = gru_wih[j * 2],        wih_r1 = gru_wih[j * 2 + 1];
  const float wih_z0 = gru_wih[(16 + j) * 2], wih_z1 = gru_wih[(16 + j) * 2 + 1];
  const float wih_n0 = gru_wih[(32 + j) * 2], wih_n1 = gru_wih[(32 + j) * 2 + 1];
  const float gb_r = gru_b[j], gb_z = gru_b[16 + j], gb_n = gru_b[32 + j];
  const float bnv = gru_bn[j];
  const float pwv = pred_w[j], pbv = pred_b[0];

  const float* xp = x_seq + (size_t)b * (T_STEPS * 2);

  float h = 0.0f;
#pragma unroll 1
  for (int t = 0; t < T_STEPS; ++t) {
    const float x0 = xp[2 * t];
    const float x1 = xp[2 * t + 1];

    // ---- adaptive Tsit5 from t=0 to t=1, <=16 iterations, early exit ----
    float y = h;
    float tt = 0.0f, dt = 1.0f;
    float k1 = mlp_f(y, w1r, b1v, w2r, b2v, w3r, b3v);
#pragma unroll 1
    for (int s = 0; s < N_ODE_STEPS; ++s) {
      // Once tt == 1.0 for every sample in the wave, the remaining reference
      // iterations are bitwise no-ops -> skip them. Wave-uniform branch.
      if (__all(tt >= 1.0f)) break;

      const float dt_c = fminf(dt, 1.0f - tt);
      const float d = dt_c;

      float s2 = 0.161f * k1;
      float k2 = mlp_f(fmaf(d, s2, y), w1r, b1v, w2r, b2v, w3r, b3v);

      float s3 = fmaf(0.335480655492357f, k2, -0.008480655492356989f * k1);
      float k3 = mlp_f(fmaf(d, s3, y), w1r, b1v, w2r, b2v, w3r, b3v);

      float s4 = fmaf(4.3622954328695815f, k3,
                 fmaf(-6.359448489975075f, k2, 2.8971530571054935f * k1));
      float k4 = mlp_f(fmaf(d, s4, y), w1r, b1v, w2r, b2v, w3r, b3v);

      float s5 = fmaf(-0.09249506636175525f, k4,
                 fmaf(7.4955393428898365f, k3,
                 fmaf(-11.748883564062828f, k2, 5.325864828439257f * k1)));
      float k5 = mlp_f(fmaf(d, s5, y), w1r, b1v, w2r, b2v, w3r, b3v);

      float s6 = fmaf(-0.028269050394068383f, k5,
                 fmaf(-0.071584973281401f, k4,
                 fmaf(8.159367898576159f, k3,
                 fmaf(-12.92096931784711f, k2, 5.86145544294642f * k1))));
      float k6 = mlp_f(fmaf(d, s6, y), w1r, b1v, w2r, b2v, w3r, b3v);

      float sy = fmaf(2.324710524099774f, k6,
                 fmaf(-3.290069515436081f, k5,
                 fmaf(1.379008574103742f, k4,
                 fmaf(0.4798896504144996f, k3,
                 fmaf(0.01f, k2, 0.09646076681806523f * k1)))));
      float y_new = fmaf(d, sy, y);

      float k7 = mlp_f(y_new, w1r, b1v, w2r, b2v, w3r, b3v);

      float se = fmaf(0.015151515151515152f, k7,
                 fmaf(-0.45808210592918697f, k6,
                 fmaf(0.5823571654525552f, k5,
                 fmaf(-0.1447110071732629f, k4,
                 fmaf(0.007880878010261995f, k3,
                 fmaf(-0.0008164344596567469f, k2, -0.001780011052225777f * k1))))));
      float err = d * se;

      float scale = fmaf(0.01f, fmaxf(fabsf(y), fabsf(y_new)), 0.0001f);
      float r = err * __builtin_amdgcn_rcpf(scale);
      float m = rsum16(r * r) * 0.0625f;   // mean over the 16 hidden dims
      float err2 = fmaxf(m, 1e-16f);

      const bool acc = err2 <= 1.0f;
      y = acc ? y_new : y;
      tt = acc ? tt + dt_c : tt;
      k1 = acc ? k7 : k1;   // FSAL: f(y_new) == k7 bitwise, else keep k1

      // err2^(-0.1) = exp2(-0.1 * log2(err2)); amdgcn logf IS v_log_f32 = log2
      float fac = 0.9f * __builtin_amdgcn_exp2f(-0.1f * __builtin_amdgcn_logf(err2));
      fac = fminf(fmaxf(fac, 0.2f), 10.0f);
      dt = dt_c * fac;
    }

    // ---- GRU update: h = n + z*(h_ev - n), h_ev = y ----
    float hr = dot16(whr, y);
    float hz = dot16(wzr, y);
    float hn = dot16(wnr, y);
    float ir = fmaf(wih_r1, x1, fmaf(wih_r0, x0, gb_r));
    float iz = fmaf(wih_z1, x1, fmaf(wih_z0, x0, gb_z));
    float in_ = fmaf(wih_n1, x1, fmaf(wih_n0, x0, gb_n));
    float rg = sigmoid_(ir + hr);
    float zg = sigmoid_(iz + hz);
    float ng = fast_tanh(fmaf(rg, hn + bnv, in_));
    h = fmaf(zg, y - ng, ng);
  }

  // ---- final projection: out[b] = h . pred_w + pred_b ----
  float ps = rsum16(h * pwv);
  if (j == 0) out[b] = ps + pbv;
}

extern "C" void kernel_launch(void* const* d_in, const int* in_sizes, int n_in,
                              void* d_out, int out_size, void* d_ws, size_t ws_size,
                              hipStream_t stream) {
  (void)in_sizes; (void)n_in; (void)out_size; (void)d_ws; (void)ws_size;
  odern_kernel<<<dim3(NB / 4), dim3(64), 0, stream>>>(
      (const float*)d_in[0],
      (const float*)d_in[1], (const float*)d_in[2],
      (const float*)d_in[3], (const float*)d_in[4],
      (const float*)d_in[5], (const float*)d_in[6],
      (const float*)d_in[7], (const float*)d_in[8],
      (const float*)d_in[9], (const float*)d_in[10],
      (const float*)d_in[11], (const float*)d_in[12],
      (float*)d_out);
}

// Round 6
// 188.518 us; speedup vs baseline: 10.0673x; 1.0221x over previous
//
#include <hip/hip_runtime.h>

// ODE-RNN encoder: B=2048, T=64, HID=16, adaptive Tsit5 + GRU.
// 16 lanes/sample, 4 samples/wave, 512 blocks x 64. Early-exit ODE loop (exact).
// Round 6: v_pk_fma_f32 dots via DPP all-gather (15 movs -> 8 packed FMAs),
// shared gather for the 3 GRU dots, biases seeded into accumulators,
// amdgpu_waves_per_eu(1,1) to give the allocator the full register budget.

#define T_STEPS 64
#define NB 2048
#define N_ODE_STEPS 16

typedef float v2f __attribute__((ext_vector_type(2)));

__device__ __forceinline__ v2f make2(float a, float b) { v2f r; r.x = a; r.y = b; return r; }

// row_ror:r  => dst lane n gets src lane (n - r) & 15 (within 16-lane row)
#define ROR(x, r) __int_as_float(__builtin_amdgcn_update_dpp( \
    0, __float_as_int(x), 0x120 + (r), 0xF, 0xF, true))

__device__ __forceinline__ float rsum16(float v) {
  v += ROR(v, 8);
  v += ROR(v, 4);
  v += ROR(v, 2);
  v += ROR(v, 1);
  return v;  // all 16 lanes hold the row sum
}

// All-gather: after this, G[p].x = y_{(j-O[2p])&15}, G[p].y = y_{(j-O[2p+1])&15}
// with O = {0,8,4,12,2,10,6,14,1,9,5,13,3,11,7,15}.
__constant__ int O_[16] = {0,8,4,12,2,10,6,14,1,9,5,13,3,11,7,15};

__device__ __forceinline__ void gather16(float y, v2f (&G)[8]) {
  float g0 = y;
  float g1 = ROR(g0, 8);
  float g2 = ROR(g0, 4);
  float g3 = ROR(g1, 4);
  float g4 = ROR(g0, 2);
  float g5 = ROR(g1, 2);
  float g6 = ROR(g2, 2);
  float g7 = ROR(g3, 2);
  float g8  = ROR(g0, 1);
  float g9  = ROR(g1, 1);
  float g10 = ROR(g2, 1);
  float g11 = ROR(g3, 1);
  float g12 = ROR(g4, 1);
  float g13 = ROR(g5, 1);
  float g14 = ROR(g6, 1);
  float g15 = ROR(g7, 1);
  G[0] = make2(g0,  g1);  G[1] = make2(g2,  g3);
  G[2] = make2(g4,  g5);  G[3] = make2(g6,  g7);
  G[4] = make2(g8,  g9);  G[5] = make2(g10, g11);
  G[6] = make2(g12, g13); G[7] = make2(g14, g15);
}

// dot = bias + sum_p W[p].G[p]  (weights pre-permuted to the gather order)
__device__ __forceinline__ float dot8pk(const v2f (&W)[8], const v2f (&G)[8], float bias) {
  v2f a0 = __builtin_elementwise_fma(G[0], W[0], make2(bias, 0.0f));
  v2f a1 = G[1] * W[1];
  a0 = __builtin_elementwise_fma(G[2], W[2], a0);
  a1 = __builtin_elementwise_fma(G[3], W[3], a1);
  a0 = __builtin_elementwise_fma(G[4], W[4], a0);
  a1 = __builtin_elementwise_fma(G[5], W[5], a1);
  a0 = __builtin_elementwise_fma(G[6], W[6], a0);
  a1 = __builtin_elementwise_fma(G[7], W[7], a1);
  v2f s = a0 + a1;
  return s.x + s.y;
}

__device__ __forceinline__ float fast_tanh(float x) {
  // tanh(x) = 1 - 2/(exp(2x)+1); exp via v_exp_f32 (computes 2^x)
  float e = __builtin_amdgcn_exp2f(x * 2.885390081777927f);  // 2*log2(e)
  return fmaf(-2.0f, __builtin_amdgcn_rcpf(e + 1.0f), 1.0f);
}

__device__ __forceinline__ float sigmoid_(float x) {
  float e = __builtin_amdgcn_exp2f(x * -1.4426950408889634f);
  return __builtin_amdgcn_rcpf(1.0f + e);
}

__device__ __forceinline__ float mlp_f(float y,
    const v2f (&w1p)[8], float b1v,
    const v2f (&w2p)[8], float b2v,
    const v2f (&w3p)[8], float b3v) {
  v2f G[8];
  gather16(y, G);
  float h1 = fast_tanh(dot8pk(w1p, G, b1v));
  gather16(h1, G);
  float h2 = fast_tanh(dot8pk(w2p, G, b2v));
  gather16(h2, G);
  return dot8pk(w3p, G, b3v);
}

__global__
__attribute__((amdgpu_flat_work_group_size(64, 64), amdgpu_waves_per_eu(1, 1)))
void odern_kernel(
    const float* __restrict__ x_seq,
    const float* __restrict__ w1, const float* __restrict__ b1,
    const float* __restrict__ w2, const float* __restrict__ b2,
    const float* __restrict__ w3, const float* __restrict__ b3,
    const float* __restrict__ gru_wih, const float* __restrict__ gru_whh,
    const float* __restrict__ gru_b, const float* __restrict__ gru_bn,
    const float* __restrict__ pred_w, const float* __restrict__ pred_b,
    float* __restrict__ out) {
  const int tid = threadIdx.x;
  const int j = tid & 15;        // hidden index owned by this lane
  const int g = tid >> 4;        // sample-in-wave 0..3
  const int b = blockIdx.x * 4 + g;

  // per-lane weight rows, pre-permuted to the gather order:
  // Wp[p] = { M[j][(j-O[2p])&15], M[j][(j-O[2p+1])&15] }
  v2f w1p[8], w2p[8], w3p[8], whp[8], wzp[8], wnp[8];
#pragma unroll
  for (int p = 0; p < 8; ++p) {
    const int ia = (j - O_[2 * p]) & 15;
    const int ib = (j - O_[2 * p + 1]) & 15;
    w1p[p] = make2(w1[j * 16 + ia], w1[j * 16 + ib]);
    w2p[p] = make2(w2[j * 16 + ia], w2[j * 16 + ib]);
    w3p[p] = make2(w3[j * 16 + ia], w3[j * 16 + ib]);
    whp[p] = make2(gru_whh[j * 16 + ia],        gru_whh[j * 16 + ib]);
    wzp[p] = make2(gru_whh[(16 + j) * 16 + ia], gru_whh[(16 + j) * 16 + ib]);
    wnp[p] = make2(gru_whh[(32 + j) * 16 + ia], gru_whh[(32 + j) * 16 + ib]);
  }
  const float b1v = b1[j], b2v = b2[j], b3v = b3[j];
  const float wih_r0 = gru_wih[j * 2],        wih_r1 = gru_wih[j * 2 + 1];
  const float wih_z0 = gru_wih[(16 + j) * 2], wih_z1 = gru_wih[(16 + j) * 2 + 1];
  const float wih_n0 = gru_wih[(32 + j) * 2], wih_n1 = gru_wih[(32 + j) * 2 + 1];
  const float gb_r = gru_b[j], gb_z = gru_b[16 + j], gb_n = gru_b[32 + j];
  const float bnv = gru_bn[j];
  const float pwv = pred_w[j], pbv = pred_b[0];

  const float* xp = x_seq + (size_t)b * (T_STEPS * 2);

  float h = 0.0f;
#pragma unroll 1
  for (int t = 0; t < T_STEPS; ++t) {
    const float x0 = xp[2 * t];
    const float x1 = xp[2 * t + 1];

    // ---- adaptive Tsit5 from t=0 to t=1, <=16 iterations, early exit ----
    float y = h;
    float tt = 0.0f, dt = 1.0f;
    float k1 = mlp_f(y, w1p, b1v, w2p, b2v, w3p, b3v);
#pragma unroll 1
    for (int s = 0; s < N_ODE_STEPS; ++s) {
      // Once tt == 1.0 for every sample in the wave, remaining reference
      // iterations are bitwise no-ops -> skip. Wave-uniform branch.
      if (__all(tt >= 1.0f)) break;

      const float dt_c = fminf(dt, 1.0f - tt);
      const float d = dt_c;

      float s2 = 0.161f * k1;
      float k2 = mlp_f(fmaf(d, s2, y), w1p, b1v, w2p, b2v, w3p, b3v);

      float s3 = fmaf(0.335480655492357f, k2, -0.008480655492356989f * k1);
      float k3 = mlp_f(fmaf(d, s3, y), w1p, b1v, w2p, b2v, w3p, b3v);

      float s4 = fmaf(4.3622954328695815f, k3,
                 fmaf(-6.359448489975075f, k2, 2.8971530571054935f * k1));
      float k4 = mlp_f(fmaf(d, s4, y), w1p, b1v, w2p, b2v, w3p, b3v);

      float s5 = fmaf(-0.09249506636175525f, k4,
                 fmaf(7.4955393428898365f, k3,
                 fmaf(-11.748883564062828f, k2, 5.325864828439257f * k1)));
      float k5 = mlp_f(fmaf(d, s5, y), w1p, b1v, w2p, b2v, w3p, b3v);

      float s6 = fmaf(-0.028269050394068383f, k5,
                 fmaf(-0.071584973281401f, k4,
                 fmaf(8.159367898576159f, k3,
                 fmaf(-12.92096931784711f, k2, 5.86145544294642f * k1))));
      float k6 = mlp_f(fmaf(d, s6, y), w1p, b1v, w2p, b2v, w3p, b3v);

      float sy = fmaf(2.324710524099774f, k6,
                 fmaf(-3.290069515436081f, k5,
                 fmaf(1.379008574103742f, k4,
                 fmaf(0.4798896504144996f, k3,
                 fmaf(0.01f, k2, 0.09646076681806523f * k1)))));
      float y_new = fmaf(d, sy, y);

      float k7 = mlp_f(y_new, w1p, b1v, w2p, b2v, w3p, b3v);

      float se = fmaf(0.015151515151515152f, k7,
                 fmaf(-0.45808210592918697f, k6,
                 fmaf(0.5823571654525552f, k5,
                 fmaf(-0.1447110071732629f, k4,
                 fmaf(0.007880878010261995f, k3,
                 fmaf(-0.0008164344596567469f, k2, -0.001780011052225777f * k1))))));
      float err = d * se;

      float scale = fmaf(0.01f, fmaxf(fabsf(y), fabsf(y_new)), 0.0001f);
      float r = err * __builtin_amdgcn_rcpf(scale);
      float m = rsum16(r * r) * 0.0625f;   // mean over the 16 hidden dims
      float err2 = fmaxf(m, 1e-16f);

      const bool acc = err2 <= 1.0f;
      y = acc ? y_new : y;
      tt = acc ? tt + dt_c : tt;
      k1 = acc ? k7 : k1;   // FSAL: f(y_new) == k7 bitwise, else keep k1

      // err2^(-0.1) = exp2(-0.1 * log2(err2)); amdgcn logf IS v_log_f32 = log2
      float fac = 0.9f * __builtin_amdgcn_exp2f(-0.1f * __builtin_amdgcn_logf(err2));
      fac = fminf(fmaxf(fac, 0.2f), 10.0f);
      dt = dt_c * fac;
    }

    // ---- GRU update: one shared gather feeds all 3 dots ----
    float ir = fmaf(wih_r1, x1, fmaf(wih_r0, x0, gb_r));
    float iz = fmaf(wih_z1, x1, fmaf(wih_z0, x0, gb_z));
    float in_ = fmaf(wih_n1, x1, fmaf(wih_n0, x0, gb_n));
    v2f G[8];
    gather16(y, G);
    float pre_r = dot8pk(whp, G, ir);    // ir + hr
    float pre_z = dot8pk(wzp, G, iz);    // iz + hz
    float hnb   = dot8pk(wnp, G, bnv);   // hn + bn
    float rg = sigmoid_(pre_r);
    float zg = sigmoid_(pre_z);
    float ng = fast_tanh(fmaf(rg, hnb, in_));
    h = fmaf(zg, y - ng, ng);
  }

  // ---- final projection: out[b] = h . pred_w + pred_b ----
  float ps = rsum16(h * pwv);
  if (j == 0) out[b] = ps + pbv;
}

extern "C" void kernel_launch(void* const* d_in, const int* in_sizes, int n_in,
                              void* d_out, int out_size, void* d_ws, size_t ws_size,
                              hipStream_t stream) {
  (void)in_sizes; (void)n_in; (void)out_size; (void)d_ws; (void)ws_size;
  odern_kernel<<<dim3(NB / 4), dim3(64), 0, stream>>>(
      (const float*)d_in[0],
      (const float*)d_in[1], (const float*)d_in[2],
      (const float*)d_in[3], (const float*)d_in[4],
      (const float*)d_in[5], (const float*)d_in[6],
      (const float*)d_in[7], (const float*)d_in[8],
      (const float*)d_in[9], (const float*)d_in[10],
      (const float*)d_in[11], (const float*)d_in[12],
      (float*)d_out);
}